// Round 11
// baseline (193.655 us; speedup 1.0000x reference)
//
#include <hip/hip_runtime.h>

// CRF NLL, round 20: both half-chains (fwd + bwd) interleaved in ONE wave.
//
// Measured: 1 chain wave/block (R12c geometry) = 520 cy/step; 2 chain
// waves/block (R17/R19) = 845 cy/step regardless of body. A chain step is
// ~80% dependency stall, so run the two INDEPENDENT chains in one wave:
// the static scheduler fills chain-F's MFMA-drain stalls with chain-B's
// instructions (issue ~2x120cy fits inside ~400cy of stall). Restores the
// verified-fast geometry: 128 threads, waves_per_eu(1,1), wave0 = dual
// chain, wave1 = gold. No LDS publish, no __syncthreads: the chains meet
// in registers (combine = 16 mul-adds + 2 shuffles).
//
// fwd:  E_s = fe_s (*) (M^T E_{s-1}), s=1..h; then V = M^T E_h (bare)
// bwd:  u_{len-1} = exp(f+trans[:,STOP]); u_s = fe_s (*) (M u_{s+1}) to h+1
// Z = sum_t V[t]*u_{h+1}[t]  (per-chain numerics identical to R19, absmax 0)
#define BB 512
#define SS 512
#define TT 64
#define START_TAG 62
#define STOP_TAG 63

#define LOG2E 1.4426950408889634f
#define LN2   0.6931471805599453f

typedef _Float16 h2 __attribute__((ext_vector_type(2)));
typedef _Float16 h8 __attribute__((ext_vector_type(8)));
typedef float    f4 __attribute__((ext_vector_type(4)));

__device__ __forceinline__ h2 pkrtz(float a, float b) {
    return __builtin_bit_cast(h2, __builtin_amdgcn_cvt_pkrtz(a, b));
}
__device__ __forceinline__ f4 MF(h8 a, h8 b, f4 c) {
    return __builtin_amdgcn_mfma_f32_16x16x32_f16(a, b, c, 0, 0, 0);
}

__global__ void __launch_bounds__(128)
__attribute__((amdgpu_waves_per_eu(1, 1))) crf_main(
    const float* __restrict__ feats, const int* __restrict__ mask,
    const int* __restrict__ tags, const float* __restrict__ trans,
    float* __restrict__ out)
{
    const int b    = blockIdx.x;
    const int tid  = threadIdx.x;
    const int lane = tid & 63;

    const float* frow = feats + (size_t)b * SS * TT;
    const int*   mrow = mask + b * SS;

    // fe rings: [0]=fwd rows, [1]=bwd rows (8 rows x 64 fp16 each)
    __shared__ __align__(16) _Float16 febuf[2][8][TT];

    int cnt = 0;
    #pragma unroll
    for (int s = lane; s < SS; s += 64) cnt += (mrow[s] != 0);
    #pragma unroll
    for (int off = 32; off; off >>= 1) cnt += __shfl_xor(cnt, off);
    const int len = cnt;            // in [SS/2, SS]
    const int h   = len >> 1;

    if (tid < 64) {
        // ============== wave 0: dual chain (fwd + bwd) ==============
        const int g  = lane >> 4;
        const int cg = lane & 15;
        const int to_base = 16 * (cg >> 2) + (cg & 3);
        const int nf = h;               // fwd steps
        const int nb = len - h - 2;     // bwd steps (nf-1 or nf-2)

        // A fragments, both orientations
        h8 Af[4][2], Ab[4][2];
        #pragma unroll
        for (int tt = 0; tt < 4; ++tt)
            #pragma unroll
            for (int kc = 0; kc < 2; ++kc)
                #pragma unroll
                for (int j = 0; j < 8; ++j) {
                    const int kt = 16 * g + 8 * kc + j;
                    const int ot = to_base + 4 * tt;
                    Af[tt][kc][j] = (_Float16)__builtin_amdgcn_exp2f(
                        trans[kt * TT + ot] * LOG2E);
                    Ab[tt][kc][j] = (_Float16)__builtin_amdgcn_exp2f(
                        trans[ot * TT + kt] * LOG2E);
                }

        // B inits (slots = raw tags 16g+sl)
        const float offs = frow[0] + trans[START_TAG * TT + 0];
        h8 Bf0, Bf1, Bb0, Bb1;
        {
            const float* fl = frow + (size_t)(len - 1) * TT;
            #pragma unroll
            for (int sl = 0; sl < 8; ++sl) {
                const int t0 = 16 * g + sl, t1 = t0 + 8;
                Bf0[sl] = (_Float16)__builtin_amdgcn_exp2f(
                    (frow[t0] + trans[START_TAG * TT + t0] - offs) * LOG2E);
                Bf1[sl] = (_Float16)__builtin_amdgcn_exp2f(
                    (frow[t1] + trans[START_TAG * TT + t1] - offs) * LOG2E);
                Bb0[sl] = (_Float16)__builtin_amdgcn_exp2f(
                    (fl[t0] + trans[t0 * TT + STOP_TAG]) * LOG2E);
                Bb1[sl] = (_Float16)__builtin_amdgcn_exp2f(
                    (fl[t1] + trans[t1 * TT + STOP_TAG]) * LOG2E);
            }
        }
        int ksf = 0, ksb = 0;

        // step i uses fe row: fwd 1+i, bwd len-2-i (no clamps needed:
        // max fe-written fwd row = nb+7 <= 261 < 512; min bwd row >= h-5 > 0)
        // prologue: fe rows for steps 0..3, both chains
        #pragma unroll
        for (int j = 0; j < 4; ++j) {
            const int rF = 1 + j, rB = len - 2 - j;
            febuf[0][rF & 7][lane] = (_Float16)__builtin_amdgcn_exp2f(
                frow[(size_t)rF * TT + lane] * LOG2E);
            febuf[1][rB & 7][lane] = (_Float16)__builtin_amdgcn_exp2f(
                frow[(size_t)rB * TT + lane] * LOG2E);
        }

        const f4 Zz = {0.f, 0.f, 0.f, 0.f};
        auto STEP = [&](const h8 (&A)[4][2], h8& B0, h8& B1,
                        int ring, int row, int& ks) {
            const _Float16* fb = &febuf[ring][row & 7][16 * g];
            const h8 feL = *(const h8*)(fb);
            const h8 feH = *(const h8*)(fb + 8);
            f4 d0 = MF(A[0][0], B0, Zz);
            f4 d1 = MF(A[1][0], B0, Zz);
            f4 d2 = MF(A[2][0], B0, Zz);
            f4 d3 = MF(A[3][0], B0, Zz);
            d0 = MF(A[0][1], B1, d0);
            d1 = MF(A[1][1], B1, d1);
            d2 = MF(A[2][1], B1, d2);
            d3 = MF(A[3][1], B1, d3);
            const int eb = (__builtin_amdgcn_readfirstlane(
                                __float_as_int(d0[0])) >> 23) & 0xff;
            ks += eb - 127;
            const float sc = __int_as_float((254 - eb) << 23);
            const h2 p0 = pkrtz(d0[0] * sc, d0[1] * sc);
            const h2 p1 = pkrtz(d0[2] * sc, d0[3] * sc);
            const h2 p2 = pkrtz(d1[0] * sc, d1[1] * sc);
            const h2 p3 = pkrtz(d1[2] * sc, d1[3] * sc);
            const h2 p4 = pkrtz(d2[0] * sc, d2[1] * sc);
            const h2 p5 = pkrtz(d2[2] * sc, d2[3] * sc);
            const h2 p6 = pkrtz(d3[0] * sc, d3[1] * sc);
            const h2 p7 = pkrtz(d3[2] * sc, d3[3] * sc);
            const h2 q0 = p0 * __builtin_shufflevector(feL, feL, 0, 1);
            const h2 q1 = p1 * __builtin_shufflevector(feL, feL, 2, 3);
            const h2 q2 = p2 * __builtin_shufflevector(feL, feL, 4, 5);
            const h2 q3 = p3 * __builtin_shufflevector(feL, feL, 6, 7);
            const h2 q4 = p4 * __builtin_shufflevector(feH, feH, 0, 1);
            const h2 q5 = p5 * __builtin_shufflevector(feH, feH, 2, 3);
            const h2 q6 = p6 * __builtin_shufflevector(feH, feH, 4, 5);
            const h2 q7 = p7 * __builtin_shufflevector(feH, feH, 6, 7);
            B0 = __builtin_shufflevector(
                     __builtin_shufflevector(q0, q1, 0, 1, 2, 3),
                     __builtin_shufflevector(q2, q3, 0, 1, 2, 3),
                     0, 1, 2, 3, 4, 5, 6, 7);
            B1 = __builtin_shufflevector(
                     __builtin_shufflevector(q4, q5, 0, 1, 2, 3),
                     __builtin_shufflevector(q6, q7, 0, 1, 2, 3),
                     0, 1, 2, 3, 4, 5, 6, 7);
        };

        int i = 0;
        for (; i + 3 < nb; i += 4) {
            // fe rows for steps i+4..i+7, both chains (read next iteration;
            // ring slots disjoint mod 8 from rows in use)
            #pragma unroll
            for (int j = 4; j < 8; ++j) {
                const int rF = 1 + i + j;
                const int rB = len - 2 - i - j;
                febuf[0][rF & 7][lane] = (_Float16)__builtin_amdgcn_exp2f(
                    frow[(size_t)rF * TT + lane] * LOG2E);
                febuf[1][rB & 7][lane] = (_Float16)__builtin_amdgcn_exp2f(
                    frow[(size_t)rB * TT + lane] * LOG2E);
            }

            STEP(Af, Bf0, Bf1, 0, 1 + i,           ksf);
            STEP(Ab, Bb0, Bb1, 1, len - 2 - i,     ksb);
            STEP(Af, Bf0, Bf1, 0, 1 + i + 1,       ksf);
            STEP(Ab, Bb0, Bb1, 1, len - 2 - i - 1, ksb);
            STEP(Af, Bf0, Bf1, 0, 1 + i + 2,       ksf);
            STEP(Ab, Bb0, Bb1, 1, len - 2 - i - 2, ksb);
            STEP(Af, Bf0, Bf1, 0, 1 + i + 3,       ksf);
            STEP(Ab, Bb0, Bb1, 1, len - 2 - i - 3, ksb);
        }

        // paired tail (fe rows i..i+2 covered by last iteration's writes)
        const int rem = nb - i;   // 0..3
        if (rem > 0) { STEP(Af, Bf0, Bf1, 0, 1 + i,     ksf);
                       STEP(Ab, Bb0, Bb1, 1, len - 2 - i,     ksb); }
        if (rem > 1) { STEP(Af, Bf0, Bf1, 0, 1 + i + 1, ksf);
                       STEP(Ab, Bb0, Bb1, 1, len - 2 - i - 1, ksb); }
        if (rem > 2) { STEP(Af, Bf0, Bf1, 0, 1 + i + 2, ksf);
                       STEP(Ab, Bb0, Bb1, 1, len - 2 - i - 2, ksb); }

        // fwd extra steps nb..nf-1 (1 or 2): write their fe rows explicitly
        for (int k = nb; k < nf; ++k) {
            const int rF = 1 + k;
            febuf[0][rF & 7][lane] = (_Float16)__builtin_amdgcn_exp2f(
                frow[(size_t)rF * TT + lane] * LOG2E);
            STEP(Af, Bf0, Bf1, 0, rF, ksf);
        }

        // V = M^T E_h (bare, rescaled) and in-register combine with u_{h+1}
        f4 d0 = MF(Af[0][0], Bf0, Zz);
        f4 d1 = MF(Af[1][0], Bf0, Zz);
        f4 d2 = MF(Af[2][0], Bf0, Zz);
        f4 d3 = MF(Af[3][0], Bf0, Zz);
        d0 = MF(Af[0][1], Bf1, d0);
        d1 = MF(Af[1][1], Bf1, d1);
        d2 = MF(Af[2][1], Bf1, d2);
        d3 = MF(Af[3][1], Bf1, d3);
        const int eb = (__builtin_amdgcn_readfirstlane(
                            __float_as_int(d0[0])) >> 23) & 0xff;
        ksf += eb - 127;
        const float sc = __int_as_float((254 - eb) << 23);

        // z_g = sum_{tt,r} V[16g+4tt+r] * u[16g+4tt+r]; slots: tt<2 -> Bb0,
        // tt>=2 -> Bb1 (replicated over cg within the 16-lane group)
        float z = 0.f;
        #pragma unroll
        for (int r = 0; r < 4; ++r) {
            z += (d0[r] * sc) * (float)Bb0[r];
            z += (d1[r] * sc) * (float)Bb0[4 + r];
            z += (d2[r] * sc) * (float)Bb1[r];
            z += (d3[r] * sc) * (float)Bb1[4 + r];
        }
        z += __shfl_xor(z, 16);
        z += __shfl_xor(z, 32);

        if (lane == 0)
            atomicAdd(out, offs + (float)(ksf + ksb) * LN2
                           + LN2 * __builtin_amdgcn_logf(z));
    } else {
        // ============== wave 1: gold score ==============
        const int* trow = tags + b * SS;
        float acc = 0.f;
        for (int s = lane; s < SS; s += 64) {
            if (mrow[s] != 0) {
                const int tag  = trow[s];
                const int prev = (s == 0) ? START_TAG : trow[s - 1];
                acc += frow[(size_t)s * TT + tag] + trans[prev * TT + tag];
            }
        }
        #pragma unroll
        for (int off = 32; off; off >>= 1) acc += __shfl_xor(acc, off);
        if (lane == 0) {
            const int end_id = trow[len - 1];
            atomicAdd(out, -(acc + trans[end_id * TT + STOP_TAG]));
        }
    }
}

extern "C" void kernel_launch(void* const* d_in, const int* in_sizes, int n_in,
                              void* d_out, int out_size, void* d_ws, size_t ws_size,
                              hipStream_t stream) {
    const float* feats = (const float*)d_in[0];   // (B,S,T) f32
    const int*   mask  = (const int*)d_in[1];     // (B,S)   int (0/1)
    const int*   tags  = (const int*)d_in[2];     // (B,S)   int
    const float* trans = (const float*)d_in[3];   // (T,T)   f32
    float* out = (float*)d_out;

    (void)hipMemsetAsync(out, 0, sizeof(float), stream);
    crf_main<<<BB, 128, 0, stream>>>(feats, mask, tags, trans, out);
}

// Round 12
// 192.884 us; speedup vs baseline: 1.0040x; 1.0040x over previous
//
#include <hip/hip_runtime.h>

// CRF NLL, round 21: dual chain in one wave with INSTRUCTION-LEVEL fusion.
//
// R20 (STEP(F); STEP(B) as separate bodies) measured ZERO overlap:
// 1078 cy/pair = 2x the single step. In-order issue means F's readfirstlane
// (which waits on F's MFMA drain) blocks B's independent MFMAs queued
// behind it. Fix: one fused STEP2 whose program order is
//   [fe loads] [F's 8 MFMAs] [B's 8 MFMAs] [F rescale+pack] [B rescale+pack]
// so B's MFMAs issue during F's drain, and B's drain hides under F's pack.
// Serial path per pair ~= one step's path.
//
// Everything else identical to R20 (passed, absmax 0.0): geometry
// (128 thr, waves_per_eu(1,1), wave0 dual chain, wave1 gold), inits,
// tails, in-register combine.
#define BB 512
#define SS 512
#define TT 64
#define START_TAG 62
#define STOP_TAG 63

#define LOG2E 1.4426950408889634f
#define LN2   0.6931471805599453f

typedef _Float16 h2 __attribute__((ext_vector_type(2)));
typedef _Float16 h8 __attribute__((ext_vector_type(8)));
typedef float    f4 __attribute__((ext_vector_type(4)));

__device__ __forceinline__ h2 pkrtz(float a, float b) {
    return __builtin_bit_cast(h2, __builtin_amdgcn_cvt_pkrtz(a, b));
}
__device__ __forceinline__ f4 MF(h8 a, h8 b, f4 c) {
    return __builtin_amdgcn_mfma_f32_16x16x32_f16(a, b, c, 0, 0, 0);
}

__global__ void __launch_bounds__(128)
__attribute__((amdgpu_waves_per_eu(1, 1))) crf_main(
    const float* __restrict__ feats, const int* __restrict__ mask,
    const int* __restrict__ tags, const float* __restrict__ trans,
    float* __restrict__ out)
{
    const int b    = blockIdx.x;
    const int tid  = threadIdx.x;
    const int lane = tid & 63;

    const float* frow = feats + (size_t)b * SS * TT;
    const int*   mrow = mask + b * SS;

    // fe rings: [0]=fwd rows, [1]=bwd rows (8 rows x 64 fp16 each)
    __shared__ __align__(16) _Float16 febuf[2][8][TT];

    int cnt = 0;
    #pragma unroll
    for (int s = lane; s < SS; s += 64) cnt += (mrow[s] != 0);
    #pragma unroll
    for (int off = 32; off; off >>= 1) cnt += __shfl_xor(cnt, off);
    const int len = cnt;            // in [SS/2, SS]
    const int h   = len >> 1;

    if (tid < 64) {
        // ============== wave 0: dual chain (fwd + bwd) ==============
        const int g  = lane >> 4;
        const int cg = lane & 15;
        const int to_base = 16 * (cg >> 2) + (cg & 3);
        const int nf = h;               // fwd steps
        const int nb = len - h - 2;     // bwd steps (nf-1 or nf-2)

        // A fragments, both orientations
        h8 Af[4][2], Ab[4][2];
        #pragma unroll
        for (int tt = 0; tt < 4; ++tt)
            #pragma unroll
            for (int kc = 0; kc < 2; ++kc)
                #pragma unroll
                for (int j = 0; j < 8; ++j) {
                    const int kt = 16 * g + 8 * kc + j;
                    const int ot = to_base + 4 * tt;
                    Af[tt][kc][j] = (_Float16)__builtin_amdgcn_exp2f(
                        trans[kt * TT + ot] * LOG2E);
                    Ab[tt][kc][j] = (_Float16)__builtin_amdgcn_exp2f(
                        trans[ot * TT + kt] * LOG2E);
                }

        // B inits (slots = raw tags 16g+sl)
        const float offs = frow[0] + trans[START_TAG * TT + 0];
        h8 Bf0, Bf1, Bb0, Bb1;
        {
            const float* fl = frow + (size_t)(len - 1) * TT;
            #pragma unroll
            for (int sl = 0; sl < 8; ++sl) {
                const int t0 = 16 * g + sl, t1 = t0 + 8;
                Bf0[sl] = (_Float16)__builtin_amdgcn_exp2f(
                    (frow[t0] + trans[START_TAG * TT + t0] - offs) * LOG2E);
                Bf1[sl] = (_Float16)__builtin_amdgcn_exp2f(
                    (frow[t1] + trans[START_TAG * TT + t1] - offs) * LOG2E);
                Bb0[sl] = (_Float16)__builtin_amdgcn_exp2f(
                    (fl[t0] + trans[t0 * TT + STOP_TAG]) * LOG2E);
                Bb1[sl] = (_Float16)__builtin_amdgcn_exp2f(
                    (fl[t1] + trans[t1 * TT + STOP_TAG]) * LOG2E);
            }
        }
        int ksf = 0, ksb = 0;

        // prologue: fe rows for steps 0..3, both chains
        #pragma unroll
        for (int j = 0; j < 4; ++j) {
            const int rF = 1 + j, rB = len - 2 - j;
            febuf[0][rF & 7][lane] = (_Float16)__builtin_amdgcn_exp2f(
                frow[(size_t)rF * TT + lane] * LOG2E);
            febuf[1][rB & 7][lane] = (_Float16)__builtin_amdgcn_exp2f(
                frow[(size_t)rB * TT + lane] * LOG2E);
        }

        const f4 Zz = {0.f, 0.f, 0.f, 0.f};

        // fused pair step: both chains' MFMAs issued before either rescale
        auto STEP2 = [&](int rowF, int rowB) {
            const _Float16* fbF = &febuf[0][rowF & 7][16 * g];
            const _Float16* fbB = &febuf[1][rowB & 7][16 * g];
            const h8 feLF = *(const h8*)(fbF);
            const h8 feHF = *(const h8*)(fbF + 8);
            const h8 feLB = *(const h8*)(fbB);
            const h8 feHB = *(const h8*)(fbB + 8);
            // --- all 16 MFMAs, F then B (independent of each other) ---
            f4 f0 = MF(Af[0][0], Bf0, Zz);
            f4 f1 = MF(Af[1][0], Bf0, Zz);
            f4 f2 = MF(Af[2][0], Bf0, Zz);
            f4 f3 = MF(Af[3][0], Bf0, Zz);
            f0 = MF(Af[0][1], Bf1, f0);
            f1 = MF(Af[1][1], Bf1, f1);
            f2 = MF(Af[2][1], Bf1, f2);
            f3 = MF(Af[3][1], Bf1, f3);
            f4 b0 = MF(Ab[0][0], Bb0, Zz);
            f4 b1 = MF(Ab[1][0], Bb0, Zz);
            f4 b2 = MF(Ab[2][0], Bb0, Zz);
            f4 b3 = MF(Ab[3][0], Bb0, Zz);
            b0 = MF(Ab[0][1], Bb1, b0);
            b1 = MF(Ab[1][1], Bb1, b1);
            b2 = MF(Ab[2][1], Bb1, b2);
            b3 = MF(Ab[3][1], Bb1, b3);
            // --- F rescale+pack (F drained during B's issue) ---
            {
                const int eb = (__builtin_amdgcn_readfirstlane(
                                    __float_as_int(f0[0])) >> 23) & 0xff;
                ksf += eb - 127;
                const float sc = __int_as_float((254 - eb) << 23);
                const h2 p0 = pkrtz(f0[0] * sc, f0[1] * sc);
                const h2 p1 = pkrtz(f0[2] * sc, f0[3] * sc);
                const h2 p2 = pkrtz(f1[0] * sc, f1[1] * sc);
                const h2 p3 = pkrtz(f1[2] * sc, f1[3] * sc);
                const h2 p4 = pkrtz(f2[0] * sc, f2[1] * sc);
                const h2 p5 = pkrtz(f2[2] * sc, f2[3] * sc);
                const h2 p6 = pkrtz(f3[0] * sc, f3[1] * sc);
                const h2 p7 = pkrtz(f3[2] * sc, f3[3] * sc);
                const h2 q0 = p0 * __builtin_shufflevector(feLF, feLF, 0, 1);
                const h2 q1 = p1 * __builtin_shufflevector(feLF, feLF, 2, 3);
                const h2 q2 = p2 * __builtin_shufflevector(feLF, feLF, 4, 5);
                const h2 q3 = p3 * __builtin_shufflevector(feLF, feLF, 6, 7);
                const h2 q4 = p4 * __builtin_shufflevector(feHF, feHF, 0, 1);
                const h2 q5 = p5 * __builtin_shufflevector(feHF, feHF, 2, 3);
                const h2 q6 = p6 * __builtin_shufflevector(feHF, feHF, 4, 5);
                const h2 q7 = p7 * __builtin_shufflevector(feHF, feHF, 6, 7);
                Bf0 = __builtin_shufflevector(
                          __builtin_shufflevector(q0, q1, 0, 1, 2, 3),
                          __builtin_shufflevector(q2, q3, 0, 1, 2, 3),
                          0, 1, 2, 3, 4, 5, 6, 7);
                Bf1 = __builtin_shufflevector(
                          __builtin_shufflevector(q4, q5, 0, 1, 2, 3),
                          __builtin_shufflevector(q6, q7, 0, 1, 2, 3),
                          0, 1, 2, 3, 4, 5, 6, 7);
            }
            // --- B rescale+pack (B drained during F's pack) ---
            {
                const int eb = (__builtin_amdgcn_readfirstlane(
                                    __float_as_int(b0[0])) >> 23) & 0xff;
                ksb += eb - 127;
                const float sc = __int_as_float((254 - eb) << 23);
                const h2 p0 = pkrtz(b0[0] * sc, b0[1] * sc);
                const h2 p1 = pkrtz(b0[2] * sc, b0[3] * sc);
                const h2 p2 = pkrtz(b1[0] * sc, b1[1] * sc);
                const h2 p3 = pkrtz(b1[2] * sc, b1[3] * sc);
                const h2 p4 = pkrtz(b2[0] * sc, b2[1] * sc);
                const h2 p5 = pkrtz(b2[2] * sc, b2[3] * sc);
                const h2 p6 = pkrtz(b3[0] * sc, b3[1] * sc);
                const h2 p7 = pkrtz(b3[2] * sc, b3[3] * sc);
                const h2 q0 = p0 * __builtin_shufflevector(feLB, feLB, 0, 1);
                const h2 q1 = p1 * __builtin_shufflevector(feLB, feLB, 2, 3);
                const h2 q2 = p2 * __builtin_shufflevector(feLB, feLB, 4, 5);
                const h2 q3 = p3 * __builtin_shufflevector(feLB, feLB, 6, 7);
                const h2 q4 = p4 * __builtin_shufflevector(feHB, feHB, 0, 1);
                const h2 q5 = p5 * __builtin_shufflevector(feHB, feHB, 2, 3);
                const h2 q6 = p6 * __builtin_shufflevector(feHB, feHB, 4, 5);
                const h2 q7 = p7 * __builtin_shufflevector(feHB, feHB, 6, 7);
                Bb0 = __builtin_shufflevector(
                          __builtin_shufflevector(q0, q1, 0, 1, 2, 3),
                          __builtin_shufflevector(q2, q3, 0, 1, 2, 3),
                          0, 1, 2, 3, 4, 5, 6, 7);
                Bb1 = __builtin_shufflevector(
                          __builtin_shufflevector(q4, q5, 0, 1, 2, 3),
                          __builtin_shufflevector(q6, q7, 0, 1, 2, 3),
                          0, 1, 2, 3, 4, 5, 6, 7);
            }
        };

        // single-chain fwd step (for the 1-2 extra fwd steps)
        auto STEPF = [&](int row) {
            const _Float16* fb = &febuf[0][row & 7][16 * g];
            const h8 feL = *(const h8*)(fb);
            const h8 feH = *(const h8*)(fb + 8);
            f4 d0 = MF(Af[0][0], Bf0, Zz);
            f4 d1 = MF(Af[1][0], Bf0, Zz);
            f4 d2 = MF(Af[2][0], Bf0, Zz);
            f4 d3 = MF(Af[3][0], Bf0, Zz);
            d0 = MF(Af[0][1], Bf1, d0);
            d1 = MF(Af[1][1], Bf1, d1);
            d2 = MF(Af[2][1], Bf1, d2);
            d3 = MF(Af[3][1], Bf1, d3);
            const int eb = (__builtin_amdgcn_readfirstlane(
                                __float_as_int(d0[0])) >> 23) & 0xff;
            ksf += eb - 127;
            const float sc = __int_as_float((254 - eb) << 23);
            const h2 p0 = pkrtz(d0[0] * sc, d0[1] * sc);
            const h2 p1 = pkrtz(d0[2] * sc, d0[3] * sc);
            const h2 p2 = pkrtz(d1[0] * sc, d1[1] * sc);
            const h2 p3 = pkrtz(d1[2] * sc, d1[3] * sc);
            const h2 p4 = pkrtz(d2[0] * sc, d2[1] * sc);
            const h2 p5 = pkrtz(d2[2] * sc, d2[3] * sc);
            const h2 p6 = pkrtz(d3[0] * sc, d3[1] * sc);
            const h2 p7 = pkrtz(d3[2] * sc, d3[3] * sc);
            const h2 q0 = p0 * __builtin_shufflevector(feL, feL, 0, 1);
            const h2 q1 = p1 * __builtin_shufflevector(feL, feL, 2, 3);
            const h2 q2 = p2 * __builtin_shufflevector(feL, feL, 4, 5);
            const h2 q3 = p3 * __builtin_shufflevector(feL, feL, 6, 7);
            const h2 q4 = p4 * __builtin_shufflevector(feH, feH, 0, 1);
            const h2 q5 = p5 * __builtin_shufflevector(feH, feH, 2, 3);
            const h2 q6 = p6 * __builtin_shufflevector(feH, feH, 4, 5);
            const h2 q7 = p7 * __builtin_shufflevector(feH, feH, 6, 7);
            Bf0 = __builtin_shufflevector(
                      __builtin_shufflevector(q0, q1, 0, 1, 2, 3),
                      __builtin_shufflevector(q2, q3, 0, 1, 2, 3),
                      0, 1, 2, 3, 4, 5, 6, 7);
            Bf1 = __builtin_shufflevector(
                      __builtin_shufflevector(q4, q5, 0, 1, 2, 3),
                      __builtin_shufflevector(q6, q7, 0, 1, 2, 3),
                      0, 1, 2, 3, 4, 5, 6, 7);
        };

        int i = 0;
        for (; i + 3 < nb; i += 4) {
            // fe rows for steps i+4..i+7, both chains
            #pragma unroll
            for (int j = 4; j < 8; ++j) {
                const int rF = 1 + i + j;
                const int rB = len - 2 - i - j;
                febuf[0][rF & 7][lane] = (_Float16)__builtin_amdgcn_exp2f(
                    frow[(size_t)rF * TT + lane] * LOG2E);
                febuf[1][rB & 7][lane] = (_Float16)__builtin_amdgcn_exp2f(
                    frow[(size_t)rB * TT + lane] * LOG2E);
            }

            STEP2(1 + i,     len - 2 - i);
            STEP2(1 + i + 1, len - 2 - i - 1);
            STEP2(1 + i + 2, len - 2 - i - 2);
            STEP2(1 + i + 3, len - 2 - i - 3);
        }

        // paired tail
        const int rem = nb - i;   // 0..3
        if (rem > 0) STEP2(1 + i,     len - 2 - i);
        if (rem > 1) STEP2(1 + i + 1, len - 2 - i - 1);
        if (rem > 2) STEP2(1 + i + 2, len - 2 - i - 2);

        // fwd extra steps nb..nf-1 (1 or 2)
        for (int k = nb; k < nf; ++k) {
            const int rF = 1 + k;
            febuf[0][rF & 7][lane] = (_Float16)__builtin_amdgcn_exp2f(
                frow[(size_t)rF * TT + lane] * LOG2E);
            STEPF(rF);
        }

        // V = M^T E_h (bare, rescaled) and in-register combine with u_{h+1}
        f4 d0 = MF(Af[0][0], Bf0, Zz);
        f4 d1 = MF(Af[1][0], Bf0, Zz);
        f4 d2 = MF(Af[2][0], Bf0, Zz);
        f4 d3 = MF(Af[3][0], Bf0, Zz);
        d0 = MF(Af[0][1], Bf1, d0);
        d1 = MF(Af[1][1], Bf1, d1);
        d2 = MF(Af[2][1], Bf1, d2);
        d3 = MF(Af[3][1], Bf1, d3);
        const int eb = (__builtin_amdgcn_readfirstlane(
                            __float_as_int(d0[0])) >> 23) & 0xff;
        ksf += eb - 127;
        const float sc = __int_as_float((254 - eb) << 23);

        float z = 0.f;
        #pragma unroll
        for (int r = 0; r < 4; ++r) {
            z += (d0[r] * sc) * (float)Bb0[r];
            z += (d1[r] * sc) * (float)Bb0[4 + r];
            z += (d2[r] * sc) * (float)Bb1[r];
            z += (d3[r] * sc) * (float)Bb1[4 + r];
        }
        z += __shfl_xor(z, 16);
        z += __shfl_xor(z, 32);

        if (lane == 0)
            atomicAdd(out, offs + (float)(ksf + ksb) * LN2
                           + LN2 * __builtin_amdgcn_logf(z));
    } else {
        // ============== wave 1: gold score ==============
        const int* trow = tags + b * SS;
        float acc = 0.f;
        for (int s = lane; s < SS; s += 64) {
            if (mrow[s] != 0) {
                const int tag  = trow[s];
                const int prev = (s == 0) ? START_TAG : trow[s - 1];
                acc += frow[(size_t)s * TT + tag] + trans[prev * TT + tag];
            }
        }
        #pragma unroll
        for (int off = 32; off; off >>= 1) acc += __shfl_xor(acc, off);
        if (lane == 0) {
            const int end_id = trow[len - 1];
            atomicAdd(out, -(acc + trans[end_id * TT + STOP_TAG]));
        }
    }
}

extern "C" void kernel_launch(void* const* d_in, const int* in_sizes, int n_in,
                              void* d_out, int out_size, void* d_ws, size_t ws_size,
                              hipStream_t stream) {
    const float* feats = (const float*)d_in[0];   // (B,S,T) f32
    const int*   mask  = (const int*)d_in[1];     // (B,S)   int (0/1)
    const int*   tags  = (const int*)d_in[2];     // (B,S)   int
    const float* trans = (const float*)d_in[3];   // (T,T)   f32
    float* out = (float*)d_out;

    (void)hipMemsetAsync(out, 0, sizeof(float), stream);
    crf_main<<<BB, 128, 0, stream>>>(feats, mask, tags, trans, out);
}